// Round 1
// 748.980 us; speedup vs baseline: 1.0393x; 1.0393x over previous
//
#include <hip/hip_runtime.h>

// ---- problem constants ----
constexpr int DIM = 768;
constexpr int NH  = 12;
constexpr int HDm = 64;
constexpr int HALF = 32;
constexpr int LATm = 256;
constexpr int NB  = 16;
constexpr int SEQ = 8192;
constexpr int NPRIME = NH * DIM;      // 9216
constexpr int PSP = 32;               // pool s-splits
constexpr int PSR = SEQ / PSP;        // 256

typedef short bf16x8 __attribute__((ext_vector_type(8)));
typedef float f32x4  __attribute__((ext_vector_type(4)));
using u16 = unsigned short;

__device__ __forceinline__ u16 f2b(float f) {
    unsigned int u = __float_as_uint(f);
    u += 0x7FFFu + ((u >> 16) & 1u);   // RNE; inputs are finite
    return (u16)(u >> 16);
}

__device__ __forceinline__ void gload_lds16(const void* g, void* l) {
    __builtin_amdgcn_global_load_lds(
        (const __attribute__((address_space(1))) unsigned int*)g,
        (__attribute__((address_space(3))) unsigned int*)l, 16, 0, 0);
}

// ---- generic batched matvec (all f32): vout[b,row] = W[row,:] . vin[b,(slice)] + bias[row]
__global__ __launch_bounds__(256) void k_mv(const float* __restrict__ Wb,
        const float* __restrict__ bias, const float* __restrict__ vin,
        float* __restrict__ vout,
        int rows, int batch, int in_bstride, int out_bstride, int headslice) {
    int w = threadIdx.x >> 6, lane = threadIdx.x & 63;
    int gw = blockIdx.x * 4 + w;
    if (gw >= rows * batch) return;
    int b = gw / rows, row = gw - b * rows;
    const float* vi = vin + (size_t)b * in_bstride + (headslice ? (row >> 6) * DIM : 0);
    const float* wr = Wb + (size_t)row * DIM;
    float acc = 0.f;
    #pragma unroll
    for (int c = 0; c < DIM / 64; ++c)
        acc += wr[c * 64 + lane] * vi[c * 64 + lane];
    #pragma unroll
    for (int off = 32; off > 0; off >>= 1) acc += __shfl_xor(acc, off, 64);
    if (lane == 0) vout[(size_t)b * out_bstride + row] = acc + bias[row];
}

// ---- fold q into Wk (RoPE cos/sin split), 1/sqrt(64) folded in. bf16 out.
__global__ void k_uw(const float* __restrict__ q, const float* __restrict__ Wk,
                     u16* __restrict__ UWpT) {
    int tid = blockIdx.x * 256 + threadIdx.x;      // 9216*64 total
    int np = tid >> 6, c = tid & 63;
    int h = np / DIM, d = np - h * DIM;
    int j = c & 31;
    float q1 = q[h * HDm + j], q2 = q[h * HDm + HALF + j];
    float wa = Wk[(size_t)(h * HDm + j) * DIM + d];
    float wb = Wk[(size_t)(h * HDm + HALF + j) * DIM + d];
    float v = (c < HALF) ? (q1 * wa + q2 * wb) : (q2 * wa - q1 * wb);
    UWpT[(size_t)np * 64 + c] = f2b(v * 0.125f);
}

// ---- trig table T[s][c]: c<32 -> cos(s*f_j), else sin(s*f_j) ----
__global__ void k_T(u16* __restrict__ T) {
    int tid = blockIdx.x * 256 + threadIdx.x;      // 8192*64
    int s = tid >> 6, c = tid & 63;
    int j = c & 31;
    float f = expf(-(float)j * (9.210340372f / 32.f));  // 10000^(-j/32)
    float ang = (float)s * f;
    float v = (c < HALF) ? cosf(ang) : sinf(ang);
    T[tid] = f2b(v);
}

// ---- Ebias[s][h] = (R(-s)q_h).bk_h * scale  (exact f32 handling of bk) ----
__global__ void k_eb(const float* __restrict__ q, const float* __restrict__ bk,
                     float* __restrict__ Ebias) {
    int tid = blockIdx.x * 256 + threadIdx.x;      // 8192*12
    if (tid >= SEQ * NH) return;
    int s = tid / NH, h = tid - s * NH;
    float acc = 0.f;
    for (int j = 0; j < HALF; ++j) {
        float f = expf(-(float)j * (9.210340372f / 32.f));
        float sv, cv; sincosf((float)s * f, &sv, &cv);
        float b1 = bk[h * HDm + j], b2 = bk[h * HDm + HALF + j];
        float q1 = q[h * HDm + j], q2 = q[h * HDm + HALF + j];
        acc += cv * (q1 * b1 + q2 * b2) + sv * (q2 * b1 - q1 * b2);
    }
    Ebias[tid] = acc * 0.125f;
}

// ---- E_chunk = T[s0:s0+cur] @ UW : M=cur, N=9216, K=64 MFMA GEMM ----
// Epilogue: LDS transpose -> 16B coalesced stores (was 64 scalar 2B stores/lane).
__global__ void __launch_bounds__(256) k_E(const u16* __restrict__ T,
        const u16* __restrict__ UWpT, u16* __restrict__ E, int s0) {
    __shared__ u16 et[4 * 64 * 72];                       // 4 waves x 64 rows x (64+8 pad)
    int lane = threadIdx.x & 63, wid = threadIdx.x >> 6;
    int m0 = blockIdx.y * 128 + (wid >> 1) * 64;          // local row in chunk
    int n0 = blockIdx.x * 128 + (wid & 1) * 64;
    int l15 = lane & 15, quad = lane >> 4;
    f32x4 acc[4][4] = {};
    #pragma unroll
    for (int kq = 0; kq < 2; ++kq) {
        int kb = kq * 32 + quad * 8;
        bf16x8 a[4], b[4];
        #pragma unroll
        for (int i = 0; i < 4; ++i)
            a[i] = *(const bf16x8*)(T + (size_t)(s0 + m0 + i * 16 + l15) * 64 + kb);
        #pragma unroll
        for (int i = 0; i < 4; ++i)
            b[i] = *(const bf16x8*)(UWpT + (size_t)(n0 + i * 16 + l15) * 64 + kb);
        #pragma unroll
        for (int mi = 0; mi < 4; ++mi)
            #pragma unroll
            for (int ni = 0; ni < 4; ++ni)
                acc[mi][ni] = __builtin_amdgcn_mfma_f32_16x16x32_bf16(a[mi], b[ni], acc[mi][ni], 0, 0, 0);
    }
    u16* ep = et + wid * (64 * 72);
    #pragma unroll
    for (int mi = 0; mi < 4; ++mi)
        #pragma unroll
        for (int ni = 0; ni < 4; ++ni) {
            int col_l = ni * 16 + l15;
            #pragma unroll
            for (int r = 0; r < 4; ++r) {
                int row_l = mi * 16 + quad * 4 + r;
                ep[row_l * 72 + col_l] = f2b(acc[mi][ni][r]);
            }
        }
    // same-wave LDS write->read: compiler inserts lgkmcnt waits; no barrier needed
    #pragma unroll
    for (int it = 0; it < 8; ++it) {
        int row_l = it * 8 + (lane >> 3);
        int cols  = (lane & 7) * 8;
        bf16x8 v = *(const bf16x8*)&ep[row_l * 72 + cols];
        *(bf16x8*)(E + (size_t)(m0 + row_l) * NPRIME + n0 + cols) = v;
    }
}

// ---- scores[b,h,s] = x[b,s,:] . E[s-s0,h,:] ; ONE s per block.
// x rows (16 b x 3KB) bulk-staged to LDS via global_load_lds (48 KB in flight/block,
// 3 blocks/CU -> ~150 KB outstanding per CU). Waves split K (6 kc each), partial
// accumulators reduced through LDS.
__global__ void __launch_bounds__(256) k_sc(const float* __restrict__ x,
        const u16* __restrict__ E, const float* __restrict__ Ebias,
        float* __restrict__ scores, int s0) {
    __shared__ float xt[16 * 772];                 // 16 rows x (768 + 4 pad) = 49,408 B
    int t = threadIdx.x, lane = t & 63, w = t >> 6;
    int sl = blockIdx.x;
    int s  = s0 + sl;
    int l15 = lane & 15, quad = lane >> 4;

    // direct E fragment loads for this wave's kc range (kc = w*6 + i)
    const u16* eb = E + (size_t)sl * NPRIME + (size_t)l15 * DIM + w * 6 * 32 + quad * 8;
    bf16x8 bv[6];
    #pragma unroll
    for (int i = 0; i < 6; ++i) bv[i] = *(const bf16x8*)(eb + i * 32);

    // stage 16 x-rows: 48 chunks of 1KB, 12 per wave
    #pragma unroll
    for (int i = 0; i < 12; ++i) {
        int idx = w * 12 + i;                      // 0..47
        int tt = idx >> 4, b = idx & 15;
        const char* g = (const char*)x + ((size_t)b * SEQ + s) * (DIM * 4) + tt * 1024 + (size_t)lane * 16;
        char* l = (char*)xt + b * 3088 + tt * 1024;
        gload_lds16(g, l);
    }
    asm volatile("s_waitcnt vmcnt(0)" ::: "memory");
    __syncthreads();

    f32x4 acc = {};
    #pragma unroll
    for (int i = 0; i < 6; ++i) {
        int kc = w * 6 + i;
        const float* xr = xt + l15 * 772 + kc * 32 + quad * 8;
        float4 fa = *(const float4*)xr;
        float4 fb = *(const float4*)(xr + 4);
        bf16x8 av;
        av[0] = (short)f2b(fa.x); av[1] = (short)f2b(fa.y);
        av[2] = (short)f2b(fa.z); av[3] = (short)f2b(fa.w);
        av[4] = (short)f2b(fb.x); av[5] = (short)f2b(fb.y);
        av[6] = (short)f2b(fb.z); av[7] = (short)f2b(fb.w);
        acc = __builtin_amdgcn_mfma_f32_16x16x32_bf16(av, bv[i], acc, 0, 0, 0);
    }
    __syncthreads();                                // xt free for reuse
    f32x4* red = (f32x4*)xt;
    red[w * 64 + lane] = acc;
    __syncthreads();
    if (t < NB * NH) {
        int b = t / NH, h = t - b * NH;
        int lr = (b >> 2) * 16 + h, r = b & 3;
        float v = red[0 * 64 + lr][r] + red[1 * 64 + lr][r]
                + red[2 * 64 + lr][r] + red[3 * 64 + lr][r];
        float bias = Ebias[s * NH + h] - exp2f(-8.f * (h + 1) / 12.f) * (float)s;
        scores[((size_t)b * NH + h) * SEQ + s] = v + bias;
    }
}

// ---- softmax over s per (b,h) row, IN PLACE ---- (1024 thr: 192 blocks were
// only 0.75 waves/SIMD at 256 thr -> latency bound)
__global__ void __launch_bounds__(1024) k_sm(float* __restrict__ scores) {
    __shared__ float red[1024];
    float* row = scores + (size_t)blockIdx.x * SEQ;
    int t = threadIdx.x;
    float m = -1e30f;
    for (int i = t; i < SEQ; i += 1024) m = fmaxf(m, row[i]);
    red[t] = m; __syncthreads();
    for (int o = 512; o > 0; o >>= 1) { if (t < o) red[t] = fmaxf(red[t], red[t + o]); __syncthreads(); }
    m = red[0]; __syncthreads();
    float sum = 0.f;
    for (int i = t; i < SEQ; i += 1024) sum += expf(row[i] - m);
    red[t] = sum; __syncthreads();
    for (int o = 512; o > 0; o >>= 1) { if (t < o) red[t] += red[t + o]; __syncthreads(); }
    float inv = 1.f / red[0];
    for (int i = t; i < SEQ; i += 1024) row[i] = expf(row[i] - m) * inv;
}

// ---- pooled_x partials with double-buffered LDS x staging ----
// block = (sp in 32, b in 16, dc in 3); 256 thr; x tiles of 16 rows x 1KB staged
// via global_load_lds ahead of compute.
__global__ void __launch_bounds__(256) k_pool(const float* __restrict__ x,
        const float* __restrict__ attn, float* __restrict__ part) {
    __shared__ float attn_s[12 * 256];             // 12 KB
    __shared__ float xbuf[2 * 16 * 256];           // 32 KB (dbuf; reused for reduce)
    int bx = blockIdx.x;                           // PSP*16*3 = 1536
    int sp = bx / 48, rem = bx - sp * 48, b = rem / 3, dc = rem - (rem / 3) * 3;
    int t = threadIdx.x, lane = t & 63, w = t >> 6;

    for (int i = t; i < 12 * 256; i += 256)
        attn_s[i] = attn[((size_t)b * NH + (i >> 8)) * SEQ + sp * PSR + (i & 255)];

    auto stage = [&](int buf, int tt) {
        #pragma unroll
        for (int jj = 0; jj < 4; ++jj) {
            int r = w * 4 + jj;
            const char* g = (const char*)x
                + (((size_t)b * SEQ + sp * PSR + tt * 16 + r) * DIM + dc * 256) * 4
                + (size_t)lane * 16;
            char* l = (char*)xbuf + buf * 16384 + r * 1024;
            gload_lds16(g, l);
        }
    };

    f32x4 acc[12] = {};
    stage(0, 0);
    asm volatile("s_waitcnt vmcnt(0)" ::: "memory");
    __syncthreads();
    for (int tt = 0; tt < 16; ++tt) {
        int cur = tt & 1;
        if (tt < 15) stage(cur ^ 1, tt + 1);       // overlap next-tile loads with compute
        const float* xb = xbuf + cur * 4096;
        #pragma unroll
        for (int j = 0; j < 4; ++j) {
            int r = w * 4 + j;
            float4 xv = *(const float4*)(xb + r * 256 + lane * 4);
            int si = tt * 16 + r;
            #pragma unroll
            for (int h = 0; h < 12; ++h) {
                float a = attn_s[h * 256 + si];
                acc[h][0] += a * xv.x; acc[h][1] += a * xv.y;
                acc[h][2] += a * xv.z; acc[h][3] += a * xv.w;
            }
        }
        asm volatile("s_waitcnt vmcnt(0)" ::: "memory");
        __syncthreads();
    }
    // cross-wave reduce via LDS (two h-halves, 24.5 KB each, fits in xbuf)
    float* red = xbuf;
    #pragma unroll
    for (int half = 0; half < 2; ++half) {
        __syncthreads();
        #pragma unroll
        for (int hh = 0; hh < 6; ++hh)
            *(f32x4*)(red + ((w * 64 + lane) * 6 + hh) * 4) = acc[half * 6 + hh];
        __syncthreads();
        for (int i = t; i < 6 * 64; i += 256) {
            int hh = i >> 6, dt = i & 63;
            f32x4 v = {};
            #pragma unroll
            for (int ww = 0; ww < 4; ++ww) {
                f32x4 u = *(const f32x4*)(red + ((ww * 64 + dt) * 6 + hh) * 4);
                v[0] += u[0]; v[1] += u[1]; v[2] += u[2]; v[3] += u[3];
            }
            *(f32x4*)(part + ((size_t)(sp * NB + b) * NH + half * 6 + hh) * DIM
                      + dc * 256 + dt * 4) = v;
        }
    }
}

__global__ void k_red(const float* __restrict__ part, float* __restrict__ pooled) {
    int i = blockIdx.x * 256 + threadIdx.x;
    if (i < NB * NH * DIM) {
        float s = 0.f;
        for (int sp = 0; sp < PSP; ++sp) s += part[(size_t)sp * (NB * NH * DIM) + i];
        pooled[i] = s;
    }
}

extern "C" void kernel_launch(void* const* d_in, const int* in_sizes, int n_in,
                              void* d_out, int out_size, void* d_ws, size_t ws_size,
                              hipStream_t stream) {
    (void)in_sizes; (void)n_in; (void)out_size;
    const float* x    = (const float*)d_in[0];
    const float* pool = (const float*)d_in[1];
    const float* Wq   = (const float*)d_in[2];
    const float* bq   = (const float*)d_in[3];
    const float* Wk   = (const float*)d_in[4];
    const float* bk   = (const float*)d_in[5];
    const float* Wv   = (const float*)d_in[6];
    const float* bv   = (const float*)d_in[7];
    const float* Wo   = (const float*)d_in[8];
    const float* bo   = (const float*)d_in[9];
    const float* Wl   = (const float*)d_in[10];
    const float* bl   = (const float*)d_in[11];

    char* w = (char*)d_ws;
    auto alloc = [&](size_t bytes) { char* p = w; w += (bytes + 255) & ~(size_t)255; return p; };
    float* q_f    = (float*)alloc(DIM * 4);
    u16*   UWpT   = (u16*)alloc((size_t)NPRIME * 64 * 2);
    u16*   Tt     = (u16*)alloc((size_t)SEQ * 64 * 2);
    float* Ebias  = (float*)alloc((size_t)SEQ * NH * 4);
    float* scores = (float*)alloc((size_t)NB * NH * SEQ * 4);   // softmax in-place -> attn
    float* part   = (float*)alloc((size_t)PSP * NB * NH * DIM * 4);
    float* pooled = (float*)alloc((size_t)NB * NH * DIM * 4);
    float* o_buf  = (float*)alloc((size_t)NB * DIM * 4);
    float* p_buf  = (float*)alloc((size_t)NB * DIM * 4);

    // adaptive E chunk: as many s-rows of E (bf16, NPRIME wide) as ws allows
    size_t fixed_used = (size_t)(w - (char*)d_ws);
    size_t margin = 65536;  // covers k_sc h>=12 slack overread + alignment
    size_t avail = (ws_size > fixed_used + margin) ? (ws_size - fixed_used - margin) : 0;
    size_t rows = avail / ((size_t)NPRIME * 2);
    int chunk = (rows >= (size_t)SEQ) ? SEQ : (int)(rows & ~(size_t)127);
    if (chunk < 128) chunk = 128;
    u16* E = (u16*)alloc((size_t)chunk * NPRIME * 2 + 8192);

    hipLaunchKernelGGL(k_mv, dim3(192), dim3(256), 0, stream,
                       Wq, bq, pool, q_f, DIM, 1, 0, DIM, 0);
    hipLaunchKernelGGL(k_uw, dim3(NPRIME * 64 / 256), dim3(256), 0, stream, q_f, Wk, UWpT);
    hipLaunchKernelGGL(k_T, dim3(SEQ * 64 / 256), dim3(256), 0, stream, Tt);
    hipLaunchKernelGGL(k_eb, dim3((SEQ * NH + 255) / 256), dim3(256), 0, stream, q_f, bk, Ebias);
    for (int s0 = 0; s0 < SEQ; s0 += chunk) {
        int cur = (SEQ - s0 < chunk) ? (SEQ - s0) : chunk;   // multiple of 128
        hipLaunchKernelGGL(k_E, dim3(NPRIME / 128, cur / 128), dim3(256), 0, stream,
                           Tt, UWpT, E, s0);
        hipLaunchKernelGGL(k_sc, dim3(cur), dim3(256), 0, stream,
                           x, E, Ebias, scores, s0);
    }
    hipLaunchKernelGGL(k_sm, dim3(NB * NH), dim3(1024), 0, stream, scores);
    hipLaunchKernelGGL(k_pool, dim3(PSP * NB * 3), dim3(256), 0, stream, x, scores, part);
    hipLaunchKernelGGL(k_red, dim3((NB * NH * DIM + 255) / 256), dim3(256), 0, stream, part, pooled);
    hipLaunchKernelGGL(k_mv, dim3(NB * DIM / 4), dim3(256), 0, stream,
                       Wv, bv, pooled, o_buf, DIM, NB, NH * DIM, DIM, 1);
    hipLaunchKernelGGL(k_mv, dim3(NB * DIM / 4), dim3(256), 0, stream,
                       Wo, bo, o_buf, p_buf, DIM, NB, DIM, DIM, 0);
    hipLaunchKernelGGL(k_mv, dim3(NB * LATm / 4), dim3(256), 0, stream,
                       Wl, bl, p_buf, (float*)d_out, LATm, NB, DIM, LATm, 0);
}

// Round 2
// 714.953 us; speedup vs baseline: 1.0888x; 1.0476x over previous
//
#include <hip/hip_runtime.h>

// ---- problem constants ----
constexpr int DIM = 768;
constexpr int NH  = 12;
constexpr int HDm = 64;
constexpr int HALF = 32;
constexpr int LATm = 256;
constexpr int NB  = 16;
constexpr int SEQ = 8192;
constexpr int NPRIME = NH * DIM;      // 9216
constexpr int PSP = 32;               // pool s-splits
constexpr int PSR = SEQ / PSP;        // 256

typedef short bf16x8 __attribute__((ext_vector_type(8)));
typedef short bf16x4 __attribute__((ext_vector_type(4)));
typedef float f32x4  __attribute__((ext_vector_type(4)));
using u16 = unsigned short;

__device__ __forceinline__ u16 f2b(float f) {
    unsigned int u = __float_as_uint(f);
    u += 0x7FFFu + ((u >> 16) & 1u);   // RNE; inputs are finite
    return (u16)(u >> 16);
}

__device__ __forceinline__ void gload_lds16(const void* g, void* l) {
    __builtin_amdgcn_global_load_lds(
        (const __attribute__((address_space(1))) unsigned int*)g,
        (__attribute__((address_space(3))) unsigned int*)l, 16, 0, 0);
}

// ---- generic batched matvec (all f32): vout[b,row] = W[row,:] . vin[b,(slice)] + bias[row]
__global__ __launch_bounds__(256) void k_mv(const float* __restrict__ Wb,
        const float* __restrict__ bias, const float* __restrict__ vin,
        float* __restrict__ vout,
        int rows, int batch, int in_bstride, int out_bstride, int headslice) {
    int w = threadIdx.x >> 6, lane = threadIdx.x & 63;
    int gw = blockIdx.x * 4 + w;
    if (gw >= rows * batch) return;
    int b = gw / rows, row = gw - b * rows;
    const float* vi = vin + (size_t)b * in_bstride + (headslice ? (row >> 6) * DIM : 0);
    const float* wr = Wb + (size_t)row * DIM;
    float acc = 0.f;
    #pragma unroll
    for (int c = 0; c < DIM / 64; ++c)
        acc += wr[c * 64 + lane] * vi[c * 64 + lane];
    #pragma unroll
    for (int off = 32; off > 0; off >>= 1) acc += __shfl_xor(acc, off, 64);
    if (lane == 0) vout[(size_t)b * out_bstride + row] = acc + bias[row];
}

// ---- fold q into Wk (RoPE cos/sin split), 1/sqrt(64) folded in. bf16 out.
__global__ void k_uw(const float* __restrict__ q, const float* __restrict__ Wk,
                     u16* __restrict__ UWpT) {
    int tid = blockIdx.x * 256 + threadIdx.x;      // 9216*64 total
    int np = tid >> 6, c = tid & 63;
    int h = np / DIM, d = np - h * DIM;
    int j = c & 31;
    float q1 = q[h * HDm + j], q2 = q[h * HDm + HALF + j];
    float wa = Wk[(size_t)(h * HDm + j) * DIM + d];
    float wb = Wk[(size_t)(h * HDm + HALF + j) * DIM + d];
    float v = (c < HALF) ? (q1 * wa + q2 * wb) : (q2 * wa - q1 * wb);
    UWpT[(size_t)np * 64 + c] = f2b(v * 0.125f);
}

// ---- trig table T[s][c]: c<32 -> cos(s*f_j), else sin(s*f_j) ----
__global__ void k_T(u16* __restrict__ T) {
    int tid = blockIdx.x * 256 + threadIdx.x;      // 8192*64
    int s = tid >> 6, c = tid & 63;
    int j = c & 31;
    float f = expf(-(float)j * (9.210340372f / 32.f));  // 10000^(-j/32)
    float ang = (float)s * f;
    float v = (c < HALF) ? cosf(ang) : sinf(ang);
    T[tid] = f2b(v);
}

// ---- Ebias[s][h] = (R(-s)q_h).bk_h * scale  (exact f32 handling of bk) ----
__global__ void k_eb(const float* __restrict__ q, const float* __restrict__ bk,
                     float* __restrict__ Ebias) {
    int tid = blockIdx.x * 256 + threadIdx.x;      // 8192*12
    if (tid >= SEQ * NH) return;
    int s = tid / NH, h = tid - s * NH;
    float acc = 0.f;
    for (int j = 0; j < HALF; ++j) {
        float f = expf(-(float)j * (9.210340372f / 32.f));
        float sv, cv; sincosf((float)s * f, &sv, &cv);
        float b1 = bk[h * HDm + j], b2 = bk[h * HDm + HALF + j];
        float q1 = q[h * HDm + j], q2 = q[h * HDm + HALF + j];
        acc += cv * (q1 * b1 + q2 * b2) + sv * (q2 * b1 - q1 * b2);
    }
    Ebias[tid] = acc * 0.125f;
}

// ---- FUSED scores kernel: per block, 16 s-values. For each 32-d chunk:
//   E_sub[s][h][dd] = T[s] @ UW[h,dc-range]  (MFMA, A=UW-rows(swap), B=T)  -> LDS
//   scores_acc[b][h][s] += x[b,s,dc-range] . E_sub                        (MFMA)
// E never touches HBM (saves ~350 MB round-trip vs k_E + k_sc).
constexpr int SBLK = 16;
constexpr int DCH  = 32;            // d per chunk
constexpr int NDC  = DIM / DCH;     // 24
constexpr int ES_S = 880;           // E_s s-stride (bytes): 12h*72 + 16 align slack
constexpr int ES_H = 72;            // E_s h-stride (bytes): 32 dd * 2B + 8 pad
constexpr int XBUF = 16 * SBLK * 128; // 32768 B per buffer

__global__ void __launch_bounds__(256) k_score(const float* __restrict__ x,
        const u16* __restrict__ Tt, const u16* __restrict__ UWpT,
        const float* __restrict__ Ebias, float* __restrict__ scores) {
    __shared__ char lds[2 * XBUF + 14464];     // 80000 B -> 2 blocks/CU
    char* es = lds + 2 * XBUF;
    int t = threadIdx.x, lane = t & 63, w = t >> 6;
    int S0 = blockIdx.x * SBLK;
    int l15 = lane & 15, quad = lane >> 4;

    // T B-fragments (B[n=s][k=c]), wave-invariant, kept in regs for whole block
    bf16x8 tb[2];
    #pragma unroll
    for (int kq = 0; kq < 2; ++kq)
        tb[kq] = *(const bf16x8*)(Tt + (size_t)(S0 + l15) * 64 + kq * 32 + quad * 8);

    // stage x chunk dc2 into buffer buf. 32 instrs/block (8/wave), 1KB each.
    // LDS dest linear; global src slot16-XOR-permuted by (b&7) so the MFMA
    // A-frag ds_read_b128s are bank-minimal.
    auto stage = [&](int buf, int dc2) {
        #pragma unroll
        for (int i = 0; i < 8; ++i) {
            int j = w * 8 + i;                    // 0..31
            int row = j * 8 + (lane >> 3);        // flat = b*16 + s_local
            int b = row >> 4, sl = row & 15;
            const char* g = (const char*)x
                + ((size_t)(b * SEQ + S0 + sl) * DIM + dc2 * DCH) * 4
                + (((lane & 7) ^ (b & 7)) * 16);
            gload_lds16(g, lds + buf * XBUF + j * 1024);
        }
    };

    stage(0, 0);                                  // prologue
    f32x4 sacc[4] = {};                           // 4 s per wave (s = w*4+si)

    for (int dc = 0; dc < NDC; ++dc) {
        int cur = dc & 1;
        // --- UW A-fragments for this chunk (issued BEFORE next-stage so the
        //     compiler's vmcnt for them leaves the stage loads in flight) ---
        bf16x8 ua[6][2];
        #pragma unroll
        for (int mt = 0; mt < 6; ++mt) {
            int npl = (w * 6 + mt) * 16 + l15;            // local n' (h,dd)
            int np = (npl >> 5) * DIM + dc * DCH + (npl & 31);
            #pragma unroll
            for (int kq = 0; kq < 2; ++kq)
                ua[mt][kq] = *(const bf16x8*)(UWpT + (size_t)np * 64 + kq * 32 + quad * 8);
        }
        if (dc < NDC - 1) stage(cur ^ 1, dc + 1);         // prefetch next chunk
        // --- E_sub = UW^T-tile x T : C[m=n'][n=s]; write 4 packed bf16/lane ---
        #pragma unroll
        for (int mt = 0; mt < 6; ++mt) {
            f32x4 ea = {};
            ea = __builtin_amdgcn_mfma_f32_16x16x32_bf16(ua[mt][0], tb[0], ea, 0, 0, 0);
            ea = __builtin_amdgcn_mfma_f32_16x16x32_bf16(ua[mt][1], tb[1], ea, 0, 0, 0);
            int npl = (w * 6 + mt) * 16 + quad * 4;       // rows quad*4..+3 (consec dd)
            int h = npl >> 5, dd0 = npl & 31;
            bf16x4 pv;
            pv[0] = (short)f2b(ea[0]); pv[1] = (short)f2b(ea[1]);
            pv[2] = (short)f2b(ea[2]); pv[3] = (short)f2b(ea[3]);
            *(bf16x4*)(es + l15 * ES_S + h * ES_H + dd0 * 2) = pv;  // col s = l15
        }
        asm volatile("s_waitcnt lgkmcnt(0)" ::: "memory");
        __builtin_amdgcn_s_barrier();                      // E_s ready (vmcnt NOT drained)
        // --- score accumulate: per s, A = x (m=b), B = E_s (n=h), K=32 ---
        const char* xb = lds + cur * XBUF;
        #pragma unroll
        for (int si = 0; si < 4; ++si) {
            int sloc = w * 4 + si;
            const char* xrow = xb + (l15 * 16 + sloc) * 128;   // b = l15
            float4 fa = *(const float4*)(xrow + (((2 * quad)     ^ (l15 & 7)) * 16));
            float4 fb = *(const float4*)(xrow + (((2 * quad + 1) ^ (l15 & 7)) * 16));
            bf16x8 av;
            av[0] = (short)f2b(fa.x); av[1] = (short)f2b(fa.y);
            av[2] = (short)f2b(fa.z); av[3] = (short)f2b(fa.w);
            av[4] = (short)f2b(fb.x); av[5] = (short)f2b(fb.y);
            av[6] = (short)f2b(fb.z); av[7] = (short)f2b(fb.w);
            const char* ep = es + sloc * ES_S + l15 * ES_H + quad * 16;  // h = l15
            bf16x4 b0 = *(const bf16x4*)ep;
            bf16x4 b1 = *(const bf16x4*)(ep + 8);
            bf16x8 bv;
            bv[0] = b0[0]; bv[1] = b0[1]; bv[2] = b0[2]; bv[3] = b0[3];
            bv[4] = b1[0]; bv[5] = b1[1]; bv[6] = b1[2]; bv[7] = b1[3];
            sacc[si] = __builtin_amdgcn_mfma_f32_16x16x32_bf16(av, bv, sacc[si], 0, 0, 0);
        }
        asm volatile("s_waitcnt lgkmcnt(0)" ::: "memory");
        __builtin_amdgcn_s_barrier();                      // E_s / x buf free
    }

    // epilogue: C[m=b][n=h]: lane col = l15 = h, rows = quad*4+r = b
    int h = l15;
    if (h < NH) {
        float slope = exp2f(-8.f * (h + 1) / 12.f);
        #pragma unroll
        for (int si = 0; si < 4; ++si) {
            int s = S0 + w * 4 + si;
            float bias = Ebias[s * NH + h] - slope * (float)s;
            #pragma unroll
            for (int r = 0; r < 4; ++r) {
                int b = quad * 4 + r;
                scores[((size_t)b * NH + h) * SEQ + s] = sacc[si][r] + bias;
            }
        }
    }
}

// ---- softmax over s per (b,h) row, IN PLACE; single pass, row cached in regs ----
__global__ void __launch_bounds__(1024) k_sm(float* __restrict__ scores) {
    __shared__ float red[1024];
    float* row = scores + (size_t)blockIdx.x * SEQ;
    int t = threadIdx.x;
    float v[8];
    float m = -1e30f;
    #pragma unroll
    for (int i = 0; i < 8; ++i) { v[i] = row[t + i * 1024]; m = fmaxf(m, v[i]); }
    red[t] = m; __syncthreads();
    for (int o = 512; o > 0; o >>= 1) { if (t < o) red[t] = fmaxf(red[t], red[t + o]); __syncthreads(); }
    m = red[0]; __syncthreads();
    float sum = 0.f;
    #pragma unroll
    for (int i = 0; i < 8; ++i) { v[i] = expf(v[i] - m); sum += v[i]; }
    red[t] = sum; __syncthreads();
    for (int o = 512; o > 0; o >>= 1) { if (t < o) red[t] += red[t + o]; __syncthreads(); }
    float inv = 1.f / red[0];
    #pragma unroll
    for (int i = 0; i < 8; ++i) row[t + i * 1024] = v[i] * inv;
}

// ---- pooled_x partials with double-buffered LDS x staging ----
__global__ void __launch_bounds__(256) k_pool(const float* __restrict__ x,
        const float* __restrict__ attn, float* __restrict__ part) {
    __shared__ float attn_s[12 * 256];             // 12 KB
    __shared__ float xbuf[2 * 16 * 256];           // 32 KB (dbuf; reused for reduce)
    int bx = blockIdx.x;                           // PSP*16*3 = 1536
    int sp = bx / 48, rem = bx - sp * 48, b = rem / 3, dc = rem - (rem / 3) * 3;
    int t = threadIdx.x, lane = t & 63, w = t >> 6;

    for (int i = t; i < 12 * 256; i += 256)
        attn_s[i] = attn[((size_t)b * NH + (i >> 8)) * SEQ + sp * PSR + (i & 255)];

    auto stage = [&](int buf, int tt) {
        #pragma unroll
        for (int jj = 0; jj < 4; ++jj) {
            int r = w * 4 + jj;
            const char* g = (const char*)x
                + (((size_t)b * SEQ + sp * PSR + tt * 16 + r) * DIM + dc * 256) * 4
                + (size_t)lane * 16;
            char* l = (char*)xbuf + buf * 16384 + r * 1024;
            gload_lds16(g, l);
        }
    };

    f32x4 acc[12] = {};
    stage(0, 0);
    asm volatile("s_waitcnt vmcnt(0)" ::: "memory");
    __syncthreads();
    for (int tt = 0; tt < 16; ++tt) {
        int cur = tt & 1;
        if (tt < 15) stage(cur ^ 1, tt + 1);       // overlap next-tile loads with compute
        const float* xb = xbuf + cur * 4096;
        #pragma unroll
        for (int j = 0; j < 4; ++j) {
            int r = w * 4 + j;
            float4 xv = *(const float4*)(xb + r * 256 + lane * 4);
            int si = tt * 16 + r;
            #pragma unroll
            for (int h = 0; h < 12; ++h) {
                float a = attn_s[h * 256 + si];
                acc[h][0] += a * xv.x; acc[h][1] += a * xv.y;
                acc[h][2] += a * xv.z; acc[h][3] += a * xv.w;
            }
        }
        asm volatile("s_waitcnt vmcnt(0)" ::: "memory");
        __syncthreads();
    }
    // cross-wave reduce via LDS (two h-halves)
    float* red = xbuf;
    #pragma unroll
    for (int half = 0; half < 2; ++half) {
        __syncthreads();
        #pragma unroll
        for (int hh = 0; hh < 6; ++hh)
            *(f32x4*)(red + ((w * 64 + lane) * 6 + hh) * 4) = acc[half * 6 + hh];
        __syncthreads();
        for (int i = t; i < 6 * 64; i += 256) {
            int hh = i >> 6, dt = i & 63;
            f32x4 v = {};
            #pragma unroll
            for (int ww = 0; ww < 4; ++ww) {
                f32x4 u = *(const f32x4*)(red + ((ww * 64 + dt) * 6 + hh) * 4);
                v[0] += u[0]; v[1] += u[1]; v[2] += u[2]; v[3] += u[3];
            }
            *(f32x4*)(part + ((size_t)(sp * NB + b) * NH + half * 6 + hh) * DIM
                      + dc * 256 + dt * 4) = v;
        }
    }
}

__global__ void k_red(const float* __restrict__ part, float* __restrict__ pooled) {
    int i = blockIdx.x * 256 + threadIdx.x;
    if (i < NB * NH * DIM) {
        float s = 0.f;
        for (int sp = 0; sp < PSP; ++sp) s += part[(size_t)sp * (NB * NH * DIM) + i];
        pooled[i] = s;
    }
}

extern "C" void kernel_launch(void* const* d_in, const int* in_sizes, int n_in,
                              void* d_out, int out_size, void* d_ws, size_t ws_size,
                              hipStream_t stream) {
    (void)in_sizes; (void)n_in; (void)out_size; (void)ws_size;
    const float* x    = (const float*)d_in[0];
    const float* pool = (const float*)d_in[1];
    const float* Wq   = (const float*)d_in[2];
    const float* bq   = (const float*)d_in[3];
    const float* Wk   = (const float*)d_in[4];
    const float* bk   = (const float*)d_in[5];
    const float* Wv   = (const float*)d_in[6];
    const float* bv   = (const float*)d_in[7];
    const float* Wo   = (const float*)d_in[8];
    const float* bo   = (const float*)d_in[9];
    const float* Wl   = (const float*)d_in[10];
    const float* bl   = (const float*)d_in[11];

    char* w = (char*)d_ws;
    auto alloc = [&](size_t bytes) { char* p = w; w += (bytes + 255) & ~(size_t)255; return p; };
    float* q_f    = (float*)alloc(DIM * 4);
    u16*   UWpT   = (u16*)alloc((size_t)NPRIME * 64 * 2);
    u16*   Tt     = (u16*)alloc((size_t)SEQ * 64 * 2);
    float* Ebias  = (float*)alloc((size_t)SEQ * NH * 4);
    float* scores = (float*)alloc((size_t)NB * NH * SEQ * 4);   // softmax in-place -> attn
    float* part   = (float*)alloc((size_t)PSP * NB * NH * DIM * 4);
    float* pooled = (float*)alloc((size_t)NB * NH * DIM * 4);
    float* o_buf  = (float*)alloc((size_t)NB * DIM * 4);
    float* p_buf  = (float*)alloc((size_t)NB * DIM * 4);

    hipLaunchKernelGGL(k_mv, dim3(192), dim3(256), 0, stream,
                       Wq, bq, pool, q_f, DIM, 1, 0, DIM, 0);
    hipLaunchKernelGGL(k_uw, dim3(NPRIME * 64 / 256), dim3(256), 0, stream, q_f, Wk, UWpT);
    hipLaunchKernelGGL(k_T, dim3(SEQ * 64 / 256), dim3(256), 0, stream, Tt);
    hipLaunchKernelGGL(k_eb, dim3((SEQ * NH + 255) / 256), dim3(256), 0, stream, q_f, bk, Ebias);
    hipLaunchKernelGGL(k_score, dim3(SEQ / SBLK), dim3(256), 0, stream,
                       x, Tt, UWpT, Ebias, scores);
    hipLaunchKernelGGL(k_sm, dim3(NB * NH), dim3(1024), 0, stream, scores);
    hipLaunchKernelGGL(k_pool, dim3(PSP * NB * 3), dim3(256), 0, stream, x, scores, part);
    hipLaunchKernelGGL(k_red, dim3((NB * NH * DIM + 255) / 256), dim3(256), 0, stream, part, pooled);
    hipLaunchKernelGGL(k_mv, dim3(NB * DIM / 4), dim3(256), 0, stream,
                       Wv, bv, pooled, o_buf, DIM, NB, NH * DIM, DIM, 1);
    hipLaunchKernelGGL(k_mv, dim3(NB * DIM / 4), dim3(256), 0, stream,
                       Wo, bo, o_buf, p_buf, DIM, NB, DIM, DIM, 0);
    hipLaunchKernelGGL(k_mv, dim3(NB * LATm / 4), dim3(256), 0, stream,
                       Wl, bl, p_buf, (float*)d_out, LATm, NB, DIM, LATm, 0);
}

// Round 3
// 713.708 us; speedup vs baseline: 1.0907x; 1.0017x over previous
//
#include <hip/hip_runtime.h>

// ---- problem constants ----
constexpr int DIM = 768;
constexpr int NH  = 12;
constexpr int HDm = 64;
constexpr int HALF = 32;
constexpr int LATm = 256;
constexpr int NB  = 16;
constexpr int SEQ = 8192;
constexpr int NPRIME = NH * DIM;      // 9216
constexpr int PSP = 32;               // pool s-splits
constexpr int PSR = SEQ / PSP;        // 256

typedef short bf16x8 __attribute__((ext_vector_type(8)));
typedef short bf16x4 __attribute__((ext_vector_type(4)));
typedef float f32x4  __attribute__((ext_vector_type(4)));
using u16 = unsigned short;

__device__ __forceinline__ u16 f2b(float f) {
    unsigned int u = __float_as_uint(f);
    u += 0x7FFFu + ((u >> 16) & 1u);   // RNE; inputs are finite
    return (u16)(u >> 16);
}

__device__ __forceinline__ void gload_lds16(const void* g, void* l) {
    __builtin_amdgcn_global_load_lds(
        (const __attribute__((address_space(1))) unsigned int*)g,
        (__attribute__((address_space(3))) unsigned int*)l, 16, 0, 0);
}

// ---- generic batched matvec (all f32): vout[b,row] = W[row,:] . vin[b,(slice)] + bias[row]
__global__ __launch_bounds__(256) void k_mv(const float* __restrict__ Wb,
        const float* __restrict__ bias, const float* __restrict__ vin,
        float* __restrict__ vout,
        int rows, int batch, int in_bstride, int out_bstride, int headslice) {
    int w = threadIdx.x >> 6, lane = threadIdx.x & 63;
    int gw = blockIdx.x * 4 + w;
    if (gw >= rows * batch) return;
    int b = gw / rows, row = gw - b * rows;
    const float* vi = vin + (size_t)b * in_bstride + (headslice ? (row >> 6) * DIM : 0);
    const float* wr = Wb + (size_t)row * DIM;
    float acc = 0.f;
    #pragma unroll
    for (int c = 0; c < DIM / 64; ++c)
        acc += wr[c * 64 + lane] * vi[c * 64 + lane];
    #pragma unroll
    for (int off = 32; off > 0; off >>= 1) acc += __shfl_xor(acc, off, 64);
    if (lane == 0) vout[(size_t)b * out_bstride + row] = acc + bias[row];
}

// ---- fold q into Wk (RoPE cos/sin split), 1/sqrt(64) folded in. bf16 out.
__global__ void k_uw(const float* __restrict__ q, const float* __restrict__ Wk,
                     u16* __restrict__ UWpT) {
    int tid = blockIdx.x * 256 + threadIdx.x;      // 9216*64 total
    int np = tid >> 6, c = tid & 63;
    int h = np / DIM, d = np - h * DIM;
    int j = c & 31;
    float q1 = q[h * HDm + j], q2 = q[h * HDm + HALF + j];
    float wa = Wk[(size_t)(h * HDm + j) * DIM + d];
    float wb = Wk[(size_t)(h * HDm + HALF + j) * DIM + d];
    float v = (c < HALF) ? (q1 * wa + q2 * wb) : (q2 * wa - q1 * wb);
    UWpT[(size_t)np * 64 + c] = f2b(v * 0.125f);
}

// ---- trig table T[s][c]: c<32 -> cos(s*f_j), else sin(s*f_j) ----
__global__ void k_T(u16* __restrict__ T) {
    int tid = blockIdx.x * 256 + threadIdx.x;      // 8192*64
    int s = tid >> 6, c = tid & 63;
    int j = c & 31;
    float f = expf(-(float)j * (9.210340372f / 32.f));  // 10000^(-j/32)
    float ang = (float)s * f;
    float v = (c < HALF) ? cosf(ang) : sinf(ang);
    T[tid] = f2b(v);
}

// ---- Ebias[s][h] = (R(-s)q_h).bk_h * scale  (exact f32 handling of bk) ----
__global__ void k_eb(const float* __restrict__ q, const float* __restrict__ bk,
                     float* __restrict__ Ebias) {
    int tid = blockIdx.x * 256 + threadIdx.x;      // 8192*12
    if (tid >= SEQ * NH) return;
    int s = tid / NH, h = tid - s * NH;
    float acc = 0.f;
    for (int j = 0; j < HALF; ++j) {
        float f = expf(-(float)j * (9.210340372f / 32.f));
        float sv, cv; sincosf((float)s * f, &sv, &cv);
        float b1 = bk[h * HDm + j], b2 = bk[h * HDm + HALF + j];
        float q1 = q[h * HDm + j], q2 = q[h * HDm + HALF + j];
        acc += cv * (q1 * b1 + q2 * b2) + sv * (q2 * b1 - q1 * b2);
    }
    Ebias[tid] = acc * 0.125f;
}

// ---- FUSED scores kernel: per block, 16 s-values. For each 32-d chunk:
//   E_sub[s][h][dd] = T[s] @ UW[h,dc-range]  (MFMA, A=UW-rows(swap), B=T)  -> LDS
//   scores_acc[b][h][s] += x[b,s,dc-range] . E_sub                        (MFMA)
// E never touches HBM. Pipelining note: ua loads are issued BEFORE stage(dc+1)
// each iteration, so the compiler's counted vmcnt for the E-MFMA drains exactly
// {stage(dc), ua(dc)} and leaves stage(dc+1) in flight -> one-ahead pipeline.
constexpr int SBLK = 16;
constexpr int DCH  = 32;            // d per chunk
constexpr int NDC  = DIM / DCH;     // 24
constexpr int ES_S = 880;           // E_s s-stride (bytes): 12h*72 + 16 align slack
constexpr int ES_H = 72;            // E_s h-stride (bytes): 32 dd * 2B + 8 pad
constexpr int XBUF = 16 * SBLK * 128; // 32768 B per buffer

__global__ void __launch_bounds__(256) k_score(const float* __restrict__ x,
        const u16* __restrict__ Tt, const u16* __restrict__ UWpT,
        const float* __restrict__ Ebias, float* __restrict__ scores) {
    __shared__ char lds[2 * XBUF + 14464];     // 80000 B -> 2 blocks/CU
    char* es = lds + 2 * XBUF;
    int t = threadIdx.x, lane = t & 63, w = t >> 6;
    int S0 = blockIdx.x * SBLK;
    int l15 = lane & 15, quad = lane >> 4;

    // T B-fragments (B[n=s][k=c]), wave-invariant, kept in regs for whole block
    bf16x8 tb[2];
    #pragma unroll
    for (int kq = 0; kq < 2; ++kq)
        tb[kq] = *(const bf16x8*)(Tt + (size_t)(S0 + l15) * 64 + kq * 32 + quad * 8);

    // stage x chunk dc2 into buffer buf. 32 instrs/block (8/wave), 1KB each.
    auto stage = [&](int buf, int dc2) {
        #pragma unroll
        for (int i = 0; i < 8; ++i) {
            int j = w * 8 + i;                    // 0..31
            int row = j * 8 + (lane >> 3);        // flat = b*16 + s_local
            int b = row >> 4, sl = row & 15;
            const char* g = (const char*)x
                + ((size_t)(b * SEQ + S0 + sl) * DIM + dc2 * DCH) * 4
                + (((lane & 7) ^ (b & 7)) * 16);
            gload_lds16(g, lds + buf * XBUF + j * 1024);
        }
    };

    stage(0, 0);                                  // prologue
    f32x4 sacc[4] = {};                           // 4 s per wave (s = w*4+si)

    for (int dc = 0; dc < NDC; ++dc) {
        int cur = dc & 1;
        // --- UW A-fragments for this chunk (BEFORE next-stage: see note) ---
        bf16x8 ua[6][2];
        #pragma unroll
        for (int mt = 0; mt < 6; ++mt) {
            int npl = (w * 6 + mt) * 16 + l15;            // local n' (h,dd)
            int np = (npl >> 5) * DIM + dc * DCH + (npl & 31);
            #pragma unroll
            for (int kq = 0; kq < 2; ++kq)
                ua[mt][kq] = *(const bf16x8*)(UWpT + (size_t)np * 64 + kq * 32 + quad * 8);
        }
        if (dc < NDC - 1) stage(cur ^ 1, dc + 1);         // prefetch next chunk
        // --- E_sub = UW^T-tile x T : C[m=n'][n=s]; write 4 packed bf16/lane ---
        #pragma unroll
        for (int mt = 0; mt < 6; ++mt) {
            f32x4 ea = {};
            ea = __builtin_amdgcn_mfma_f32_16x16x32_bf16(ua[mt][0], tb[0], ea, 0, 0, 0);
            ea = __builtin_amdgcn_mfma_f32_16x16x32_bf16(ua[mt][1], tb[1], ea, 0, 0, 0);
            int npl = (w * 6 + mt) * 16 + quad * 4;       // rows quad*4..+3 (consec dd)
            int h = npl >> 5, dd0 = npl & 31;
            bf16x4 pv;
            pv[0] = (short)f2b(ea[0]); pv[1] = (short)f2b(ea[1]);
            pv[2] = (short)f2b(ea[2]); pv[3] = (short)f2b(ea[3]);
            *(bf16x4*)(es + l15 * ES_S + h * ES_H + dd0 * 2) = pv;  // col s = l15
        }
        asm volatile("s_waitcnt lgkmcnt(0)" ::: "memory");
        __builtin_amdgcn_s_barrier();                      // E_s ready (vmcnt NOT drained)
        // --- score accumulate: per s, A = x (m=b), B = E_s (n=h), K=32 ---
        const char* xb = lds + cur * XBUF;
        #pragma unroll
        for (int si = 0; si < 4; ++si) {
            int sloc = w * 4 + si;
            const char* xrow = xb + (l15 * 16 + sloc) * 128;   // b = l15
            float4 fa = *(const float4*)(xrow + (((2 * quad)     ^ (l15 & 7)) * 16));
            float4 fb = *(const float4*)(xrow + (((2 * quad + 1) ^ (l15 & 7)) * 16));
            bf16x8 av;
            av[0] = (short)f2b(fa.x); av[1] = (short)f2b(fa.y);
            av[2] = (short)f2b(fa.z); av[3] = (short)f2b(fa.w);
            av[4] = (short)f2b(fb.x); av[5] = (short)f2b(fb.y);
            av[6] = (short)f2b(fb.z); av[7] = (short)f2b(fb.w);
            const char* ep = es + sloc * ES_S + l15 * ES_H + quad * 16;  // h = l15
            bf16x4 b0 = *(const bf16x4*)ep;
            bf16x4 b1 = *(const bf16x4*)(ep + 8);
            bf16x8 bv;
            bv[0] = b0[0]; bv[1] = b0[1]; bv[2] = b0[2]; bv[3] = b0[3];
            bv[4] = b1[0]; bv[5] = b1[1]; bv[6] = b1[2]; bv[7] = b1[3];
            sacc[si] = __builtin_amdgcn_mfma_f32_16x16x32_bf16(av, bv, sacc[si], 0, 0, 0);
        }
        asm volatile("s_waitcnt lgkmcnt(0)" ::: "memory");
        __builtin_amdgcn_s_barrier();                      // E_s / x buf free
    }

    // epilogue: C[m=b][n=h]: lane col = l15 = h, rows = quad*4+r = b
    int h = l15;
    if (h < NH) {
        float slope = exp2f(-8.f * (h + 1) / 12.f);
        #pragma unroll
        for (int si = 0; si < 4; ++si) {
            int s = S0 + w * 4 + si;
            float bias = Ebias[s * NH + h] - slope * (float)s;
            #pragma unroll
            for (int r = 0; r < 4; ++r) {
                int b = quad * 4 + r;
                scores[((size_t)b * NH + h) * SEQ + s] = sacc[si][r] + bias;
            }
        }
    }
}

// ---- softmax over s per (b,h) row, IN PLACE; single pass, row cached in regs ----
__global__ void __launch_bounds__(1024) k_sm(float* __restrict__ scores) {
    __shared__ float red[1024];
    float* row = scores + (size_t)blockIdx.x * SEQ;
    int t = threadIdx.x;
    float v[8];
    float m = -1e30f;
    #pragma unroll
    for (int i = 0; i < 8; ++i) { v[i] = row[t + i * 1024]; m = fmaxf(m, v[i]); }
    red[t] = m; __syncthreads();
    for (int o = 512; o > 0; o >>= 1) { if (t < o) red[t] = fmaxf(red[t], red[t + o]); __syncthreads(); }
    m = red[0]; __syncthreads();
    float sum = 0.f;
    #pragma unroll
    for (int i = 0; i < 8; ++i) { v[i] = expf(v[i] - m); sum += v[i]; }
    red[t] = sum; __syncthreads();
    for (int o = 512; o > 0; o >>= 1) { if (t < o) red[t] += red[t + o]; __syncthreads(); }
    float inv = 1.f / red[0];
    #pragma unroll
    for (int i = 0; i < 8; ++i) row[t + i * 1024] = v[i] * inv;
}

// ---- pooled_x partials, v3: barrier-free pipelined staging ----
// Key invariant: wave w stages AND reads only rows [w*4, w*4+4) of each tile,
// so tile buffers are wave-private -> no intra-loop barriers; per-wave counted
// vmcnt is the only sync. 3 buffers, 2 tiles ahead. sp REVERSED so the first
// blocks read the x-tail that k_score just left in L3 (256 MB of the 402).
__global__ void __launch_bounds__(256) k_pool(const float* __restrict__ x,
        const float* __restrict__ attn, float* __restrict__ part) {
    __shared__ float attn_s[12 * 256];             // 12 KB
    __shared__ float xbuf[3 * 16 * 256];           // 48 KB, 3 tile buffers
    int bx = blockIdx.x;                           // PSP*16*3 = 1536
    int spr = bx / 48, rem = bx - spr * 48, b = rem / 3, dc = rem - (rem / 3) * 3;
    int sp = (PSP - 1) - spr;                      // L3-warm tail first
    int t = threadIdx.x, lane = t & 63, w = t >> 6;

    auto stage = [&](int buf, int tt) {
        #pragma unroll
        for (int jj = 0; jj < 4; ++jj) {
            int r = w * 4 + jj;
            const char* g = (const char*)x
                + (((size_t)b * SEQ + sp * PSR + tt * 16 + r) * DIM + dc * 256) * 4
                + (size_t)lane * 16;
            char* l = (char*)xbuf + buf * 16384 + r * 1024;
            gload_lds16(g, l);
        }
    };

    stage(0, 0);                                   // 2 tiles in flight before attn
    stage(1, 1);
    for (int i = t; i < 12 * 256; i += 256)
        attn_s[i] = attn[((size_t)b * NH + (i >> 8)) * SEQ + sp * PSR + (i & 255)];
    asm volatile("s_waitcnt lgkmcnt(0)" ::: "memory");
    __builtin_amdgcn_s_barrier();                  // attn ready; x DMA stays in flight

    f32x4 acc[12] = {};
    for (int tt = 0; tt < 16; ++tt) {
        if (tt < 15) asm volatile("s_waitcnt vmcnt(4)" ::: "memory");  // tile tt landed
        else         asm volatile("s_waitcnt vmcnt(0)" ::: "memory");  // last tile
        const float* xb = xbuf + (tt % 3) * 4096;
        #pragma unroll
        for (int j = 0; j < 4; ++j) {
            int r = w * 4 + j;
            float4 xv = *(const float4*)(xb + r * 256 + lane * 4);
            int si = tt * 16 + r;
            #pragma unroll
            for (int h = 0; h < 12; ++h) {
                float a = attn_s[h * 256 + si];
                acc[h][0] += a * xv.x; acc[h][1] += a * xv.y;
                acc[h][2] += a * xv.z; acc[h][3] += a * xv.w;
            }
        }
        if (tt + 2 < 16) stage((tt + 2) % 3, tt + 2);   // keep 2 ahead
    }
    // cross-wave reduce via LDS (two h-halves); all DMA landed (vmcnt(0) above)
    float* red = xbuf;
    #pragma unroll
    for (int half = 0; half < 2; ++half) {
        __syncthreads();
        #pragma unroll
        for (int hh = 0; hh < 6; ++hh)
            *(f32x4*)(red + ((w * 64 + lane) * 6 + hh) * 4) = acc[half * 6 + hh];
        __syncthreads();
        for (int i = t; i < 6 * 64; i += 256) {
            int hh = i >> 6, dt = i & 63;
            f32x4 v = {};
            #pragma unroll
            for (int ww = 0; ww < 4; ++ww) {
                f32x4 u = *(const f32x4*)(red + ((ww * 64 + dt) * 6 + hh) * 4);
                v[0] += u[0]; v[1] += u[1]; v[2] += u[2]; v[3] += u[3];
            }
            *(f32x4*)(part + ((size_t)(sp * NB + b) * NH + half * 6 + hh) * DIM
                      + dc * 256 + dt * 4) = v;
        }
    }
}

__global__ void k_red(const float* __restrict__ part, float* __restrict__ pooled) {
    int i = blockIdx.x * 256 + threadIdx.x;
    if (i < NB * NH * DIM) {
        float s = 0.f;
        for (int sp = 0; sp < PSP; ++sp) s += part[(size_t)sp * (NB * NH * DIM) + i];
        pooled[i] = s;
    }
}

extern "C" void kernel_launch(void* const* d_in, const int* in_sizes, int n_in,
                              void* d_out, int out_size, void* d_ws, size_t ws_size,
                              hipStream_t stream) {
    (void)in_sizes; (void)n_in; (void)out_size; (void)ws_size;
    const float* x    = (const float*)d_in[0];
    const float* pool = (const float*)d_in[1];
    const float* Wq   = (const float*)d_in[2];
    const float* bq   = (const float*)d_in[3];
    const float* Wk   = (const float*)d_in[4];
    const float* bk   = (const float*)d_in[5];
    const float* Wv   = (const float*)d_in[6];
    const float* bv   = (const float*)d_in[7];
    const float* Wo   = (const float*)d_in[8];
    const float* bo   = (const float*)d_in[9];
    const float* Wl   = (const float*)d_in[10];
    const float* bl   = (const float*)d_in[11];

    char* w = (char*)d_ws;
    auto alloc = [&](size_t bytes) { char* p = w; w += (bytes + 255) & ~(size_t)255; return p; };
    float* q_f    = (float*)alloc(DIM * 4);
    u16*   UWpT   = (u16*)alloc((size_t)NPRIME * 64 * 2);
    u16*   Tt     = (u16*)alloc((size_t)SEQ * 64 * 2);
    float* Ebias  = (float*)alloc((size_t)SEQ * NH * 4);
    float* scores = (float*)alloc((size_t)NB * NH * SEQ * 4);   // softmax in-place -> attn
    float* part   = (float*)alloc((size_t)PSP * NB * NH * DIM * 4);
    float* pooled = (float*)alloc((size_t)NB * NH * DIM * 4);
    float* o_buf  = (float*)alloc((size_t)NB * DIM * 4);
    float* p_buf  = (float*)alloc((size_t)NB * DIM * 4);

    hipLaunchKernelGGL(k_mv, dim3(192), dim3(256), 0, stream,
                       Wq, bq, pool, q_f, DIM, 1, 0, DIM, 0);
    hipLaunchKernelGGL(k_uw, dim3(NPRIME * 64 / 256), dim3(256), 0, stream, q_f, Wk, UWpT);
    hipLaunchKernelGGL(k_T, dim3(SEQ * 64 / 256), dim3(256), 0, stream, Tt);
    hipLaunchKernelGGL(k_eb, dim3((SEQ * NH + 255) / 256), dim3(256), 0, stream, q_f, bk, Ebias);
    hipLaunchKernelGGL(k_score, dim3(SEQ / SBLK), dim3(256), 0, stream,
                       x, Tt, UWpT, Ebias, scores);
    hipLaunchKernelGGL(k_sm, dim3(NB * NH), dim3(1024), 0, stream, scores);
    hipLaunchKernelGGL(k_pool, dim3(PSP * NB * 3), dim3(256), 0, stream, x, scores, part);
    hipLaunchKernelGGL(k_red, dim3((NB * NH * DIM + 255) / 256), dim3(256), 0, stream, part, pooled);
    hipLaunchKernelGGL(k_mv, dim3(NB * DIM / 4), dim3(256), 0, stream,
                       Wv, bv, pooled, o_buf, DIM, NB, NH * DIM, DIM, 1);
    hipLaunchKernelGGL(k_mv, dim3(NB * DIM / 4), dim3(256), 0, stream,
                       Wo, bo, o_buf, p_buf, DIM, NB, DIM, DIM, 0);
    hipLaunchKernelGGL(k_mv, dim3(NB * LATm / 4), dim3(256), 0, stream,
                       Wl, bl, p_buf, (float*)d_out, LATm, NB, DIM, LATm, 0);
}